// Round 1
// baseline (9264.535 us; speedup 1.0000x reference)
//
#include <hip/hip_runtime.h>

// -------- Tiled MLP layer, transposed activation layout: buf[dim][64] -------
// 256 threads = 16 edge-groups (et) x 16 neuron-lanes (jt).
// Each thread: 4 edges (et*4..et*4+3) x up to NG=ceil(DO/16) neurons (jt+16g).
template<int DI, int DO, bool RELU>
__device__ __forceinline__ void mlp_layer_t(
    const float* __restrict__ W,   // [DI][DO] row-major
    const float* __restrict__ B,   // [DO]
    float (*in)[64],               // LDS, rows = DI
    float (*out)[64],              // LDS, rows = DO
    int tid)
{
    const int et = tid & 15;
    const int jt = tid >> 4;
    constexpr int NG = (DO + 15) / 16;

    float acc0[NG], acc1[NG], acc2[NG], acc3[NG];
#pragma unroll
    for (int g = 0; g < NG; ++g) {
        const int j = jt + 16 * g;
        const float bb = (j < DO) ? B[j] : 0.f;
        acc0[g] = bb; acc1[g] = bb; acc2[g] = bb; acc3[g] = bb;
    }

    for (int k = 0; k < DI; ++k) {
        const float4 a = *(const float4*)&in[k][et * 4];   // ds_read_b128
#pragma unroll
        for (int g = 0; g < NG; ++g) {
            const int j = jt + 16 * g;
            const float w = (j < DO) ? W[k * DO + j] : 0.f;
            acc0[g] = fmaf(a.x, w, acc0[g]);
            acc1[g] = fmaf(a.y, w, acc1[g]);
            acc2[g] = fmaf(a.z, w, acc2[g]);
            acc3[g] = fmaf(a.w, w, acc3[g]);
        }
    }

#pragma unroll
    for (int g = 0; g < NG; ++g) {
        const int j = jt + 16 * g;
        if (j < DO) {
            float4 v;
            v.x = acc0[g]; v.y = acc1[g]; v.z = acc2[g]; v.w = acc3[g];
            if (RELU) {
                v.x = fmaxf(v.x, 0.f); v.y = fmaxf(v.y, 0.f);
                v.z = fmaxf(v.z, 0.f); v.w = fmaxf(v.w, 0.f);
            }
            *(float4*)&out[j][et * 4] = v;                 // ds_write_b128
        }
    }
}

// ------------------------------- Edge kernel --------------------------------
// 64 edges / block. R' = [O[src](6), O[tgt](6), t] -> fR MLP -> atomicAdd E'.
__global__ __launch_bounds__(256, 2) void edge_kernel(
    const float* __restrict__ t,
    const float* __restrict__ x,      // [N,4]
    const float* __restrict__ Ofx,    // [N,2]
    const int*   __restrict__ src,
    const int*   __restrict__ tgt,
    const float* __restrict__ W0, const float* __restrict__ B0,  // 13x150
    const float* __restrict__ W1, const float* __restrict__ B1,  // 150x150
    const float* __restrict__ W2, const float* __restrict__ B2,  // 150x150
    const float* __restrict__ W3, const float* __restrict__ B3,  // 150x150
    const float* __restrict__ W4, const float* __restrict__ B4,  // 150x50
    float* __restrict__ Eprime,       // [N,50] (pre-zeroed)
    int n_edges)
{
    __shared__ float bufA[152][64];
    __shared__ float bufB[152][64];
    __shared__ int   tgt_s[64];

    const int tid = threadIdx.x;
    const int e0  = blockIdx.x * 64;

    // ---- load R' tile (transposed: bufA[dim][edge]) ----
    {
        const int e = tid & 63;
        const int q = tid >> 6;
        const int ge = e0 + e;
        const bool valid = (ge < n_edges);
        if (q == 0) {
            const int s = valid ? src[ge] : 0;
            float4 v = valid ? *(const float4*)&x[(size_t)s * 4] : float4{0, 0, 0, 0};
            bufA[0][e] = v.x; bufA[1][e] = v.y; bufA[2][e] = v.z; bufA[3][e] = v.w;
        } else if (q == 1) {
            const int s = valid ? src[ge] : 0;
            float2 v = valid ? *(const float2*)&Ofx[(size_t)s * 2] : float2{0, 0};
            bufA[4][e] = v.x; bufA[5][e] = v.y;
            bufA[12][e] = valid ? t[0] : 0.f;
        } else if (q == 2) {
            const int g = valid ? tgt[ge] : 0;
            float4 v = valid ? *(const float4*)&x[(size_t)g * 4] : float4{0, 0, 0, 0};
            bufA[6][e] = v.x; bufA[7][e] = v.y; bufA[8][e] = v.z; bufA[9][e] = v.w;
        } else {
            const int g = valid ? tgt[ge] : 0;
            float2 v = valid ? *(const float2*)&Ofx[(size_t)g * 2] : float2{0, 0};
            bufA[10][e] = v.x; bufA[11][e] = v.y;
            tgt_s[e] = valid ? g : -1;
        }
    }
    __syncthreads();

    mlp_layer_t<13, 150, true >(W0, B0, bufA, bufB, tid); __syncthreads();
    mlp_layer_t<150, 150, true >(W1, B1, bufB, bufA, tid); __syncthreads();
    mlp_layer_t<150, 150, true >(W2, B2, bufA, bufB, tid); __syncthreads();
    mlp_layer_t<150, 150, true >(W3, B3, bufB, bufA, tid); __syncthreads();
    mlp_layer_t<150, 50, false>(W4, B4, bufA, bufB, tid); __syncthreads();

    // ---- scatter-add E tile into Eprime ----
    for (int idx = tid; idx < 50 * 64; idx += 256) {
        const int j = idx >> 6;       // 0..49  (wave-uniform)
        const int e = idx & 63;       // lane-contiguous -> conflict-free LDS read
        const int g = tgt_s[e];
        if (g >= 0) atomicAdd(&Eprime[(size_t)g * 50 + j], bufB[j][e]);
    }
}

// ------------------------------- Node kernel --------------------------------
__global__ __launch_bounds__(256, 2) void node_kernel(
    const float* __restrict__ Eprime,                 // [N,50]
    const float* __restrict__ W0, const float* __restrict__ B0,  // 50x100
    const float* __restrict__ W1, const float* __restrict__ B1,  // 100x4
    float* __restrict__ P,                            // [N,4]
    int n_nodes)
{
    __shared__ float bufA[104][64];
    __shared__ float bufB[104][64];

    const int tid = threadIdx.x;
    const int n0  = blockIdx.x * 64;

    // load E' tile (coalesced over global, transposed into LDS)
    for (int idx = tid; idx < 64 * 50; idx += 256) {
        const int e = idx / 50;
        const int k = idx - e * 50;
        const int n = n0 + e;
        bufA[k][e] = (n < n_nodes) ? Eprime[(size_t)n * 50 + k] : 0.f;
    }
    __syncthreads();

    mlp_layer_t<50, 100, true >(W0, B0, bufA, bufB, tid); __syncthreads();
    mlp_layer_t<100, 4, false>(W1, B1, bufB, bufA, tid); __syncthreads();

    for (int idx = tid; idx < 64 * 4; idx += 256) {
        const int e = idx & 63;
        const int j = idx >> 6;
        const int n = n0 + e;
        if (n < n_nodes) P[(size_t)n * 4 + j] = bufA[j][e];
    }
}

// ------------------------------- launcher -----------------------------------
extern "C" void kernel_launch(void* const* d_in, const int* in_sizes, int n_in,
                              void* d_out, int out_size, void* d_ws, size_t ws_size,
                              hipStream_t stream)
{
    const float* t   = (const float*)d_in[0];
    const float* x   = (const float*)d_in[1];
    const float* Ofx = (const float*)d_in[2];
    const int*   src = (const int*)d_in[3];
    const int*   tgt = (const int*)d_in[4];
    const float* W0  = (const float*)d_in[5];  const float* B0 = (const float*)d_in[6];
    const float* W1  = (const float*)d_in[7];  const float* B1 = (const float*)d_in[8];
    const float* W2  = (const float*)d_in[9];  const float* B2 = (const float*)d_in[10];
    const float* W3  = (const float*)d_in[11]; const float* B3 = (const float*)d_in[12];
    const float* W4  = (const float*)d_in[13]; const float* B4 = (const float*)d_in[14];
    const float* OW0 = (const float*)d_in[15]; const float* OB0 = (const float*)d_in[16];
    const float* OW1 = (const float*)d_in[17]; const float* OB1 = (const float*)d_in[18];

    const int n_nodes = in_sizes[1] / 4;
    const int n_edges = in_sizes[3];

    float* Eprime = (float*)d_ws;   // [n_nodes][50] fp32 = 20 MB
    hipMemsetAsync(Eprime, 0, (size_t)n_nodes * 50 * sizeof(float), stream);

    edge_kernel<<<dim3((n_edges + 63) / 64), dim3(256), 0, stream>>>(
        t, x, Ofx, src, tgt, W0, B0, W1, B1, W2, B2, W3, B3, W4, B4,
        Eprime, n_edges);

    node_kernel<<<dim3((n_nodes + 63) / 64), dim3(256), 0, stream>>>(
        Eprime, OW0, OB0, OW1, OB1, (float*)d_out, n_nodes);
}

// Round 2
// 1347.501 us; speedup vs baseline: 6.8753x; 6.8753x over previous
//
#include <hip/hip_runtime.h>

typedef unsigned short u16;
typedef __attribute__((ext_vector_type(8))) short short8;
typedef __attribute__((ext_vector_type(4))) float f32x4;

constexpr int SA    = 168;          // act row stride (bf16 elems): 336B, 16B-aligned, 2-way banks
constexpr int SW    = 168;          // weight row stride
constexpr int NPAD  = 160;
constexpr int WSLOT = NPAD * SW;    // 26880 elems = 53760 B per layer slot
constexpr int BLK_E = 256;          // edges per block
constexpr int NTHR  = 512;          // 8 waves = 4 M-groups x 2 N-groups

__device__ __forceinline__ u16 f2bf(float f) {  // RNE f32->bf16
    union { float f; unsigned u; } c; c.f = f;
    return (u16)((c.u + 0x7fffu + ((c.u >> 16) & 1u)) >> 16);
}

// ---- prep: W[DI][DO] fp32 -> Wt[n][k] bf16, zero-padded to [160][168] ----
__global__ void prep_weights(const float* __restrict__ W0, const float* __restrict__ W1,
                             const float* __restrict__ W2, const float* __restrict__ W3,
                             const float* __restrict__ W4, u16* __restrict__ out)
{
    const int l = blockIdx.y;
    const float* W; int DI, DO;
    if      (l == 0) { W = W0; DI = 13;  DO = 150; }
    else if (l == 1) { W = W1; DI = 150; DO = 150; }
    else if (l == 2) { W = W2; DI = 150; DO = 150; }
    else if (l == 3) { W = W3; DI = 150; DO = 150; }
    else             { W = W4; DI = 150; DO = 50;  }
    u16* dst = out + (size_t)l * WSLOT;
    for (int idx = blockIdx.x * blockDim.x + threadIdx.x; idx < WSLOT;
         idx += gridDim.x * blockDim.x) {
        const int n = idx / SW, k = idx - n * SW;
        const float v = (n < DO && k < DI) ? W[k * DO + n] : 0.f;
        dst[idx] = f2bf(v);
    }
}

// ---- stage one padded weight slot into LDS ----
__device__ __forceinline__ void stage_w(const u16* __restrict__ g, u16* s, int tid) {
    const uint4* gs = (const uint4*)g;
    uint4* ss = (uint4*)s;
    for (int i = tid; i < WSLOT / 8; i += NTHR) ss[i] = gs[i];
}

// ---- MFMA tile compute: wave = 4 M-tiles x NT N-tiles, K = KS*32 ----
template<int KS, int NT>
__device__ __forceinline__ void gemm_tiles(const u16* act, const u16* wbuf,
        int mg, int ng, int col, int quad, f32x4 (&acc)[4][NT])
{
#pragma unroll
    for (int i = 0; i < 4; ++i)
#pragma unroll
        for (int j = 0; j < NT; ++j)
            acc[i][j] = f32x4{0.f, 0.f, 0.f, 0.f};

#pragma unroll
    for (int ks = 0; ks < KS; ++ks) {
        const int koff = ks * 32 + quad * 8;
        short8 a[4];
#pragma unroll
        for (int i = 0; i < 4; ++i)
            a[i] = *(const short8*)&act[(mg * 64 + i * 16 + col) * SA + koff];
#pragma unroll
        for (int j = 0; j < NT; ++j) {
            const int n = (ng * NT + j) * 16 + col;
            const short8 b = *(const short8*)&wbuf[n * SW + koff];
#pragma unroll
            for (int i = 0; i < 4; ++i)
                acc[i][j] = __builtin_amdgcn_mfma_f32_16x16x32_bf16(a[i], b, acc[i][j], 0, 0, 0);
        }
    }
}

// ---- epilogue: bias + relu + bf16, write act in place (C: row=quad*4+r, col=lane&15)
template<int NT>
__device__ __forceinline__ void store_act(u16* act, const float* __restrict__ bias, int DO,
        int mg, int ng, int col, int quad, f32x4 (&acc)[4][NT])
{
#pragma unroll
    for (int j = 0; j < NT; ++j) {
        const int n = (ng * NT + j) * 16 + col;
        const float bb = (n < DO) ? bias[n] : 0.f;   // n>=DO cols: acc==0 (zeroed W rows) -> store 0
#pragma unroll
        for (int i = 0; i < 4; ++i)
#pragma unroll
            for (int r = 0; r < 4; ++r) {
                const float v = fmaxf(acc[i][j][r] + bb, 0.f);
                act[(mg * 64 + i * 16 + quad * 4 + r) * SA + n] = f2bf(v);
            }
    }
}

// ------------------------------- Edge kernel --------------------------------
__global__ __launch_bounds__(NTHR, 2) void edge_kernel(
    const float* __restrict__ t, const float* __restrict__ x, const float* __restrict__ Ofx,
    const int* __restrict__ src, const int* __restrict__ tgt,
    const u16* __restrict__ Wt,
    const float* __restrict__ B0, const float* __restrict__ B1, const float* __restrict__ B2,
    const float* __restrict__ B3, const float* __restrict__ B4,
    float* __restrict__ Ep, int n_edges)
{
    __shared__ __align__(16) u16 act[BLK_E * SA];    // 86016 B, in-place layer buffer
    __shared__ __align__(16) u16 wbuf[WSLOT];        // 53760 B, current layer weights
    __shared__ int tgt_s[BLK_E];                     // 1 KB

    const int tid  = threadIdx.x;
    const int lane = tid & 63;
    const int w    = tid >> 6;
    const int col  = lane & 15;
    const int quad = lane >> 4;
    const int mg   = w & 3;     // M-group: edges [mg*64, mg*64+64)
    const int ng   = w >> 2;    // N-group

    // ---- gather R' = [O[src](6), O[tgt](6), t, 0-pad..32) ----
    {
        const int e = tid >> 1;
        const long long ge = (long long)blockIdx.x * BLK_E + e;
        const bool valid = ge < n_edges;
        u16* row = &act[e * SA];
        if ((tid & 1) == 0) {
            const int s = valid ? src[ge] : 0;
            const float4 xv = valid ? *(const float4*)&x[(size_t)s * 4] : float4{0, 0, 0, 0};
            const float2 ov = valid ? *(const float2*)&Ofx[(size_t)s * 2] : float2{0, 0};
            row[0] = f2bf(xv.x); row[1] = f2bf(xv.y); row[2] = f2bf(xv.z); row[3] = f2bf(xv.w);
            row[4] = f2bf(ov.x); row[5] = f2bf(ov.y);
        } else {
            const int g = valid ? tgt[ge] : 0;
            const float4 xv = valid ? *(const float4*)&x[(size_t)g * 4] : float4{0, 0, 0, 0};
            const float2 ov = valid ? *(const float2*)&Ofx[(size_t)g * 2] : float2{0, 0};
            row[6]  = f2bf(xv.x); row[7]  = f2bf(xv.y); row[8] = f2bf(xv.z); row[9] = f2bf(xv.w);
            row[10] = f2bf(ov.x); row[11] = f2bf(ov.y);
            row[12] = valid ? f2bf(t[0]) : (u16)0;
            for (int k = 13; k < 32; ++k) row[k] = 0;
            tgt_s[e] = valid ? g : -1;
        }
    }

    stage_w(Wt + 0 * WSLOT, wbuf, tid);
    __syncthreads();

    f32x4 acc[4][5];

    gemm_tiles<1, 5>(act, wbuf, mg, ng, col, quad, acc);    // L0: 13(pad32)->150
    __syncthreads();
    store_act<5>(act, B0, 150, mg, ng, col, quad, acc);
    stage_w(Wt + 1 * WSLOT, wbuf, tid);
    __syncthreads();

    gemm_tiles<5, 5>(act, wbuf, mg, ng, col, quad, acc);    // L1: 150->150
    __syncthreads();
    store_act<5>(act, B1, 150, mg, ng, col, quad, acc);
    stage_w(Wt + 2 * WSLOT, wbuf, tid);
    __syncthreads();

    gemm_tiles<5, 5>(act, wbuf, mg, ng, col, quad, acc);    // L2
    __syncthreads();
    store_act<5>(act, B2, 150, mg, ng, col, quad, acc);
    stage_w(Wt + 3 * WSLOT, wbuf, tid);
    __syncthreads();

    gemm_tiles<5, 5>(act, wbuf, mg, ng, col, quad, acc);    // L3
    __syncthreads();
    store_act<5>(act, B3, 150, mg, ng, col, quad, acc);
    stage_w(Wt + 4 * WSLOT, wbuf, tid);
    __syncthreads();

    f32x4 acc4[4][2];
    gemm_tiles<5, 2>(act, wbuf, mg, ng, col, quad, acc4);   // L4: 150->50 (pad 64), linear

    // ---- scatter-add E into Ep[tgt][50]; per instr: 4 nodes x 64B contiguous ----
#pragma unroll
    for (int j = 0; j < 2; ++j) {
        const int n = (ng * 2 + j) * 16 + col;
        if (n < 50) {
            const float bb = B4[n];
#pragma unroll
            for (int i = 0; i < 4; ++i)
#pragma unroll
                for (int r = 0; r < 4; ++r) {
                    const int e = mg * 64 + i * 16 + quad * 4 + r;
                    const int g = tgt_s[e];
                    if (g >= 0) atomicAdd(&Ep[(size_t)g * 50 + n], acc4[i][j][r] + bb);
                }
        }
    }
}

// ---------------- Node kernel (fp32, unchanged from R1 — small cost) --------
template<int DI, int DO, bool RELU>
__device__ __forceinline__ void mlp_layer_t(
    const float* __restrict__ W, const float* __restrict__ B,
    float (*in)[64], float (*out)[64], int tid)
{
    const int et = tid & 15;
    const int jt = tid >> 4;
    constexpr int NG = (DO + 15) / 16;

    float acc0[NG], acc1[NG], acc2[NG], acc3[NG];
#pragma unroll
    for (int g = 0; g < NG; ++g) {
        const int j = jt + 16 * g;
        const float bb = (j < DO) ? B[j] : 0.f;
        acc0[g] = bb; acc1[g] = bb; acc2[g] = bb; acc3[g] = bb;
    }
    for (int k = 0; k < DI; ++k) {
        const float4 a = *(const float4*)&in[k][et * 4];
#pragma unroll
        for (int g = 0; g < NG; ++g) {
            const int j = jt + 16 * g;
            const float wv = (j < DO) ? W[k * DO + j] : 0.f;
            acc0[g] = fmaf(a.x, wv, acc0[g]);
            acc1[g] = fmaf(a.y, wv, acc1[g]);
            acc2[g] = fmaf(a.z, wv, acc2[g]);
            acc3[g] = fmaf(a.w, wv, acc3[g]);
        }
    }
#pragma unroll
    for (int g = 0; g < NG; ++g) {
        const int j = jt + 16 * g;
        if (j < DO) {
            float4 v; v.x = acc0[g]; v.y = acc1[g]; v.z = acc2[g]; v.w = acc3[g];
            if (RELU) {
                v.x = fmaxf(v.x, 0.f); v.y = fmaxf(v.y, 0.f);
                v.z = fmaxf(v.z, 0.f); v.w = fmaxf(v.w, 0.f);
            }
            *(float4*)&out[j][et * 4] = v;
        }
    }
}

__global__ __launch_bounds__(256, 2) void node_kernel(
    const float* __restrict__ Eprime,
    const float* __restrict__ W0, const float* __restrict__ B0,
    const float* __restrict__ W1, const float* __restrict__ B1,
    float* __restrict__ P, int n_nodes)
{
    __shared__ float bufA[104][64];
    __shared__ float bufB[104][64];
    const int tid = threadIdx.x;
    const int n0  = blockIdx.x * 64;

    for (int idx = tid; idx < 64 * 50; idx += 256) {
        const int e = idx / 50;
        const int k = idx - e * 50;
        const int n = n0 + e;
        bufA[k][e] = (n < n_nodes) ? Eprime[(size_t)n * 50 + k] : 0.f;
    }
    __syncthreads();
    mlp_layer_t<50, 100, true >(W0, B0, bufA, bufB, tid); __syncthreads();
    mlp_layer_t<100, 4, false>(W1, B1, bufB, bufA, tid); __syncthreads();
    for (int idx = tid; idx < 64 * 4; idx += 256) {
        const int e = idx & 63;
        const int j = idx >> 6;
        const int n = n0 + e;
        if (n < n_nodes) P[(size_t)n * 4 + j] = bufA[j][e];
    }
}

// ------------------------------- launcher -----------------------------------
extern "C" void kernel_launch(void* const* d_in, const int* in_sizes, int n_in,
                              void* d_out, int out_size, void* d_ws, size_t ws_size,
                              hipStream_t stream)
{
    const float* t   = (const float*)d_in[0];
    const float* x   = (const float*)d_in[1];
    const float* Ofx = (const float*)d_in[2];
    const int*   src = (const int*)d_in[3];
    const int*   tgt = (const int*)d_in[4];
    const float* W0  = (const float*)d_in[5];  const float* B0 = (const float*)d_in[6];
    const float* W1  = (const float*)d_in[7];  const float* B1 = (const float*)d_in[8];
    const float* W2  = (const float*)d_in[9];  const float* B2 = (const float*)d_in[10];
    const float* W3  = (const float*)d_in[11]; const float* B3 = (const float*)d_in[12];
    const float* W4  = (const float*)d_in[13]; const float* B4 = (const float*)d_in[14];
    const float* OW0 = (const float*)d_in[15]; const float* OB0 = (const float*)d_in[16];
    const float* OW1 = (const float*)d_in[17]; const float* OB1 = (const float*)d_in[18];

    const int n_nodes = in_sizes[1] / 4;
    const int n_edges = in_sizes[3];

    float* Ep = (float*)d_ws;                                        // [N,50] fp32 = 20 MB
    u16*   Wt = (u16*)((char*)d_ws + (size_t)n_nodes * 50 * sizeof(float)); // 5 x 53760 B

    prep_weights<<<dim3(32, 5), 256, 0, stream>>>(W0, W1, W2, W3, W4, Wt);
    hipMemsetAsync(Ep, 0, (size_t)n_nodes * 50 * sizeof(float), stream);

    edge_kernel<<<(n_edges + BLK_E - 1) / BLK_E, NTHR, 0, stream>>>(
        t, x, Ofx, src, tgt, Wt, B0, B1, B2, B3, B4, Ep, n_edges);

    node_kernel<<<(n_nodes + 63) / 64, 256, 0, stream>>>(
        Ep, OW0, OB0, OW1, OB1, (float*)d_out, n_nodes);
}